// Round 1
// baseline (140.432 us; speedup 1.0000x reference)
//
#include <hip/hip_runtime.h>
#include <hip/hip_bf16.h>

using bf16x8 = __attribute__((ext_vector_type(8))) short;   // 8 bf16 (16 B)
using f32x4  = __attribute__((ext_vector_type(4))) float;   // MFMA C/D frag

#define NN 1024
#define DD 128

// ---------------- kernel 0: zero rowsum ----------------
__global__ void init_kernel(float* __restrict__ rowsum) {
    int i = blockIdx.x * 256 + threadIdx.x;
    if (i < 2 * NN) rowsum[i] = 0.0f;
}

// ---------------- kernel 1: h = S@Win^T -> M(bf16); values = (S*g)@Wout^T ----------------
__global__ __launch_bounds__(256) void prep_kernel(
    const float* __restrict__ states, const float* __restrict__ gates,
    const float* __restrict__ W_in, const float* __restrict__ W_out,
    __hip_bfloat16* __restrict__ M_bf, float* __restrict__ values)
{
    __shared__ float s_state[8 * 128];
    __shared__ float s_h[8 * 128];
    __shared__ float s_WinT[32 * 129];   // [kk][d], pad 129 -> conflict-free
    __shared__ float s_WoutT[32 * 129];
    __shared__ float s_g[8];

    const int tid = threadIdx.x;
    const int b  = blockIdx.x >> 7;          // 128 blocks per batch
    const int n0 = (blockIdx.x & 127) * 8;   // 8 rows per block

    const float* sb = states + ((size_t)b * NN + n0) * DD;
    for (int idx = tid; idx < 8 * 128; idx += 256) s_state[idx] = sb[idx];
    if (tid < 8) s_g[tid] = gates[b * NN + n0 + tid];

    const int c  = tid & 127;   // output column d
    const int rg = tid >> 7;    // row half: rows rg*4 .. rg*4+3
    float acc_h[4] = {0.f, 0.f, 0.f, 0.f};
    float acc_v[4] = {0.f, 0.f, 0.f, 0.f};

    const int kk = tid & 31;
    const int dg = tid >> 5;
    for (int k0 = 0; k0 < 128; k0 += 32) {
        __syncthreads();
        #pragma unroll
        for (int dd = 0; dd < 16; ++dd) {
            int d = dg * 16 + dd;
            s_WinT [kk * 129 + d] = W_in [d * 128 + k0 + kk];
            s_WoutT[kk * 129 + d] = W_out[d * 128 + k0 + kk];
        }
        __syncthreads();
        #pragma unroll
        for (int k2 = 0; k2 < 32; ++k2) {
            float w1 = s_WinT [k2 * 129 + c];
            float w2 = s_WoutT[k2 * 129 + c];
            #pragma unroll
            for (int r = 0; r < 4; ++r) {
                float s = s_state[(rg * 4 + r) * 128 + k0 + k2];
                acc_h[r] = fmaf(s, w1, acc_h[r]);
                acc_v[r] = fmaf(s, w2, acc_v[r]);
            }
        }
    }

    #pragma unroll
    for (int r = 0; r < 4; ++r) {
        int row = rg * 4 + r;
        s_h[row * 128 + c] = acc_h[r];
        values[((size_t)b * NN + n0 + row) * DD + c] = acc_v[r] * s_g[row];
    }
    __syncthreads();

    // M[row][2p]   = (h[2p]+eps)  / hypot
    // M[row][2p+1] = (h[2p+1]+eps)/ hypot    (== cos/sin of atan2)
    #pragma unroll
    for (int r = 0; r < 4; ++r) {
        int row = rg * 4 + r;
        int p2 = c & ~1;
        float x = s_h[row * 128 + p2]     + 1e-8f;
        float y = s_h[row * 128 + p2 + 1] + 1e-8f;
        float r2 = x * x + y * y;
        float out;
        if (r2 > 0.f) out = ((c & 1) ? y : x) * rsqrtf(r2);
        else          out = (c & 1) ? 0.f : 1.f;   // atan2(0,0)=0 -> cos=1,sin=0
        M_bf[((size_t)b * NN + n0 + row) * DD + c] = __float2bfloat16(out);
    }
}

// ---------------- kernel 2: S=M@M^T/64 -> r_new (out) + coupling(bf16, ws) + rowsums ----------------
__global__ __launch_bounds__(256) void resonance_kernel(
    const __hip_bfloat16* __restrict__ M_bf,
    const float* __restrict__ r_acc,
    const float* __restrict__ gates,
    const float* __restrict__ cond_ptr,
    float* __restrict__ r_out,
    __hip_bfloat16* __restrict__ c_bf,
    float* __restrict__ rowsum)
{
    const int tid = threadIdx.x;
    const int l  = tid & 63;
    const int w  = tid >> 6;                 // wave id: rows i0 + w*16
    const int j0 = blockIdx.x * 64;
    const int i0 = blockIdx.y * 64;
    const int b  = blockIdx.z;

    const int row_a = l & 15;
    const int kg    = l >> 4;

    const bf16x8* Mv = (const bf16x8*)(M_bf + (size_t)b * NN * DD);  // 16 groups of 8 per row

    f32x4 acc[4];
    #pragma unroll
    for (int cp = 0; cp < 4; ++cp) acc[cp] = (f32x4){0.f, 0.f, 0.f, 0.f};

    #pragma unroll
    for (int ks = 0; ks < 4; ++ks) {
        int kv = ks * 4 + kg;                // k = kv*8
        bf16x8 a = Mv[(size_t)(i0 + w * 16 + row_a) * 16 + kv];
        #pragma unroll
        for (int cp = 0; cp < 4; ++cp) {
            bf16x8 bb = Mv[(size_t)(j0 + cp * 16 + row_a) * 16 + kv];
            acc[cp] = __builtin_amdgcn_mfma_f32_16x16x32_bf16(a, bb, acc[cp], 0, 0, 0);
        }
    }

    float cond = fminf(fmaxf(cond_ptr[0], -5.f), 5.f);
    const int i_base = i0 + w * 16 + kg * 4;

    float g_j[4], g_i[4];
    #pragma unroll
    for (int cp = 0; cp < 4; ++cp) g_j[cp] = gates[b * NN + j0 + cp * 16 + row_a];
    #pragma unroll
    for (int q = 0; q < 4; ++q)    g_i[q]  = gates[b * NN + i_base + q];

    const size_t robase = (size_t)b * NN * NN;
    float rs[4] = {0.f, 0.f, 0.f, 0.f};

    #pragma unroll
    for (int q = 0; q < 4; ++q) {
        int i = i_base + q;     // C/D: row = kg*4+q  [m89-verified]
        float gi = g_i[q];
        #pragma unroll
        for (int cp = 0; cp < 4; ++cp) {
            int j = j0 + cp * 16 + row_a;    // C/D: col = lane&15
            float s  = acc[cp][q] * (1.f / 64.f);
            float ra = r_acc[robase + (size_t)i * NN + j];
            float rn = fminf(fmaxf(0.7f * ra + 0.3f * s, -2.f), 2.f);
            r_out[robase + (size_t)i * NN + j] = rn;
            float cpl = (i == j) ? 0.f
                        : (1.f / (1.f + __expf(-cond * rn))) * gi * g_j[cp];
            c_bf[robase + (size_t)i * NN + j] = __float2bfloat16(cpl);
            rs[q] += cpl;
        }
    }

    // reduce each row's partial over the 16 lanes sharing (kg,q)
    #pragma unroll
    for (int q = 0; q < 4; ++q) {
        float v = rs[q];
        v += __shfl_xor(v, 1);
        v += __shfl_xor(v, 2);
        v += __shfl_xor(v, 4);
        v += __shfl_xor(v, 8);
        if ((l & 15) == 0) atomicAdd(&rowsum[b * NN + i_base + q], v);
    }
}

// ---------------- kernel 3: field = (c @ values) / rowsum ----------------
__global__ __launch_bounds__(256) void gather_kernel(
    const __hip_bfloat16* __restrict__ c_bf,
    const float* __restrict__ values,
    const float* __restrict__ rowsum,
    float* __restrict__ field)
{
    __shared__ float s_c[8 * 257];   // [row][j], pad 257

    const int tid = threadIdx.x;
    const int d4  = (tid & 31) * 4;  // this thread's 4 output columns
    const int row = tid >> 5;        // this thread's row (0..7)
    const int b     = blockIdx.x >> 7;
    const int rbase = (blockIdx.x & 127) * 8;

    const float* val_b = values + (size_t)b * NN * DD;
    const __hip_bfloat16* c_rows = c_bf + ((size_t)b * NN + rbase) * NN;

    float4 acc = {0.f, 0.f, 0.f, 0.f};

    for (int jc = 0; jc < 4; ++jc) {
        int j0 = jc * 256;
        {   // stage 8x256 coupling chunk -> f32 LDS (each thread: 8 bf16 = 16 B)
            int srow = tid >> 5;
            int jj   = (tid & 31) * 8;
            const uint4 raw = *(const uint4*)(c_rows + (size_t)srow * NN + j0 + jj);
            unsigned int u[4] = {raw.x, raw.y, raw.z, raw.w};
            #pragma unroll
            for (int t = 0; t < 4; ++t) {
                float f0 = __uint_as_float(u[t] << 16);
                float f1 = __uint_as_float(u[t] & 0xffff0000u);
                s_c[srow * 257 + jj + 2 * t]     = f0;
                s_c[srow * 257 + jj + 2 * t + 1] = f1;
            }
        }
        __syncthreads();
        #pragma unroll 8
        for (int j = 0; j < 256; ++j) {
            float4 v = *(const float4*)(val_b + (size_t)(j0 + j) * DD + d4);
            float cj = s_c[row * 257 + j];
            acc.x = fmaf(cj, v.x, acc.x);
            acc.y = fmaf(cj, v.y, acc.y);
            acc.z = fmaf(cj, v.z, acc.z);
            acc.w = fmaf(cj, v.w, acc.w);
        }
        __syncthreads();
    }

    float inv = 1.0f / (rowsum[b * NN + rbase + row] + 1e-8f);
    float4 o = {acc.x * inv, acc.y * inv, acc.z * inv, acc.w * inv};
    *(float4*)(field + ((size_t)b * NN + rbase + row) * DD + d4) = o;
}

// ---------------- launch ----------------
extern "C" void kernel_launch(void* const* d_in, const int* in_sizes, int n_in,
                              void* d_out, int out_size, void* d_ws, size_t ws_size,
                              hipStream_t stream) {
    const float* states = (const float*)d_in[0];
    const float* gates  = (const float*)d_in[1];
    const float* r_acc  = (const float*)d_in[2];
    const float* W_in   = (const float*)d_in[3];
    const float* W_out  = (const float*)d_in[4];
    const float* cond   = (const float*)d_in[5];

    float* field = (float*)d_out;                 // (2,1024,128)
    float* r_out = field + 2 * NN * DD;           // (2,1024,1024)

    char* ws = (char*)d_ws;
    __hip_bfloat16* M_bf  = (__hip_bfloat16*)ws;                                  // 512 KB
    float*          values = (float*)(ws + (512 << 10));                          // 1 MB
    __hip_bfloat16* c_bf  = (__hip_bfloat16*)(ws + (512 << 10) + (1 << 20));      // 4 MB
    float*          rowsum = (float*)(ws + (512 << 10) + (1 << 20) + (4 << 20));  // 8 KB

    hipLaunchKernelGGL(init_kernel, dim3(8), dim3(256), 0, stream, rowsum);
    hipLaunchKernelGGL(prep_kernel, dim3(256), dim3(256), 0, stream,
                       states, gates, W_in, W_out, M_bf, values);
    hipLaunchKernelGGL(resonance_kernel, dim3(16, 16, 2), dim3(256), 0, stream,
                       M_bf, r_acc, gates, cond, r_out, c_bf, rowsum);
    hipLaunchKernelGGL(gather_kernel, dim3(256), dim3(256), 0, stream,
                       c_bf, values, rowsum, field);
}

// Round 2
// 110.555 us; speedup vs baseline: 1.2702x; 1.2702x over previous
//
#include <hip/hip_runtime.h>
#include <hip/hip_bf16.h>

using bf16x8 = __attribute__((ext_vector_type(8))) short;   // 8 bf16 (16 B)
using f32x4  = __attribute__((ext_vector_type(4))) float;   // MFMA C/D frag

#define NN 1024
#define DD 128

// ---------------- kernel 0: zero rowsum ----------------
__global__ void init_kernel(float* __restrict__ rowsum) {
    int i = blockIdx.x * 256 + threadIdx.x;
    if (i < 2 * NN) rowsum[i] = 0.0f;
}

// ---- kernel 1: h = S@Win^T -> M(bf16); valT = ((S*g)@Wout^T)^T (bf16) ----
// 512 blocks, 4 rows each. (cos,sin) pair partner fetched via shfl_xor(1).
__global__ __launch_bounds__(256) void prep_kernel(
    const float* __restrict__ states, const float* __restrict__ gates,
    const float* __restrict__ W_in, const float* __restrict__ W_out,
    __hip_bfloat16* __restrict__ M_bf, __hip_bfloat16* __restrict__ valT)
{
    __shared__ float s_state[4 * 128];
    __shared__ float s_WinT[32 * 129];   // [kk][d], pad -> conflict-free
    __shared__ float s_WoutT[32 * 129];
    __shared__ float s_g[4];

    const int tid = threadIdx.x;
    const int b  = blockIdx.x >> 8;          // 256 blocks per batch
    const int n0 = (blockIdx.x & 255) * 4;   // 4 rows per block

    const float* sb = states + ((size_t)b * NN + n0) * DD;
    if (tid < 128) ((float4*)s_state)[tid] = ((const float4*)sb)[tid];
    if (tid < 4)   s_g[tid] = gates[b * NN + n0 + tid];

    const int c  = tid & 127;   // output column d
    const int rg = tid >> 7;    // rows rg*2 .. rg*2+1
    float acc_h[2] = {0.f, 0.f};
    float acc_v[2] = {0.f, 0.f};

    const int kk = tid & 31;
    const int dg = tid >> 5;
    for (int k0 = 0; k0 < 128; k0 += 32) {
        __syncthreads();
        #pragma unroll
        for (int dd = 0; dd < 16; ++dd) {
            int d = dg * 16 + dd;
            s_WinT [kk * 129 + d] = W_in [d * 128 + k0 + kk];
            s_WoutT[kk * 129 + d] = W_out[d * 128 + k0 + kk];
        }
        __syncthreads();
        #pragma unroll
        for (int k2 = 0; k2 < 32; ++k2) {
            float w1 = s_WinT [k2 * 129 + c];
            float w2 = s_WoutT[k2 * 129 + c];
            #pragma unroll
            for (int r = 0; r < 2; ++r) {
                float s = s_state[(rg * 2 + r) * 128 + k0 + k2];
                acc_h[r] = fmaf(s, w1, acc_h[r]);
                acc_v[r] = fmaf(s, w2, acc_v[r]);
            }
        }
    }

    #pragma unroll
    for (int r = 0; r < 2; ++r) {
        int row = rg * 2 + r;
        float hm = acc_h[r] + 1e-8f;         // my (h+eps)
        float hp = __shfl_xor(hm, 1);        // pair partner (c^1 <-> tid^1, same wave)
        float x = (c & 1) ? hp : hm;
        float y = (c & 1) ? hm : hp;
        float r2 = x * x + y * y;
        float out;
        if (r2 > 0.f) out = ((c & 1) ? y : x) * rsqrtf(r2);
        else          out = (c & 1) ? 0.f : 1.f;   // atan2(0,0)=0 -> cos=1,sin=0
        M_bf[((size_t)b * NN + n0 + row) * DD + c] = __float2bfloat16(out);
        valT[((size_t)b * DD + c) * NN + n0 + row] = __float2bfloat16(acc_v[r] * s_g[row]);
    }
}

// ---- kernel 2: S=M@M^T/64 -> r_new (out) + coupling(bf16, ws) + rowsums ----
// 64 i x 32 j tiles -> 1024 blocks (4/CU, 16 waves/CU).
__global__ __launch_bounds__(256) void resonance_kernel(
    const __hip_bfloat16* __restrict__ M_bf,
    const float* __restrict__ r_acc,
    const float* __restrict__ gates,
    const float* __restrict__ cond_ptr,
    float* __restrict__ r_out,
    __hip_bfloat16* __restrict__ c_bf,
    float* __restrict__ rowsum)
{
    const int tid = threadIdx.x;
    const int l  = tid & 63;
    const int w  = tid >> 6;                 // wave id: rows i0 + w*16
    const int j0 = blockIdx.x * 32;
    const int i0 = blockIdx.y * 64;
    const int b  = blockIdx.z;

    const int row_a = l & 15;
    const int kg    = l >> 4;

    const bf16x8* Mv = (const bf16x8*)(M_bf + (size_t)b * NN * DD);  // 16 groups of 8 per row

    f32x4 acc[2];
    #pragma unroll
    for (int cp = 0; cp < 2; ++cp) acc[cp] = (f32x4){0.f, 0.f, 0.f, 0.f};

    #pragma unroll
    for (int ks = 0; ks < 4; ++ks) {
        int kv = ks * 4 + kg;                // k = kv*8
        bf16x8 a = Mv[(size_t)(i0 + w * 16 + row_a) * 16 + kv];
        #pragma unroll
        for (int cp = 0; cp < 2; ++cp) {
            bf16x8 bb = Mv[(size_t)(j0 + cp * 16 + row_a) * 16 + kv];
            acc[cp] = __builtin_amdgcn_mfma_f32_16x16x32_bf16(a, bb, acc[cp], 0, 0, 0);
        }
    }

    float cond = fminf(fmaxf(cond_ptr[0], -5.f), 5.f);
    const int i_base = i0 + w * 16 + kg * 4;

    float g_j[2], g_i[4];
    #pragma unroll
    for (int cp = 0; cp < 2; ++cp) g_j[cp] = gates[b * NN + j0 + cp * 16 + row_a];
    #pragma unroll
    for (int q = 0; q < 4; ++q)    g_i[q]  = gates[b * NN + i_base + q];

    const size_t robase = (size_t)b * NN * NN;
    float rs[4] = {0.f, 0.f, 0.f, 0.f};

    #pragma unroll
    for (int q = 0; q < 4; ++q) {
        int i = i_base + q;     // C/D: row = kg*4+q  [m89-verified]
        float gi = g_i[q];
        #pragma unroll
        for (int cp = 0; cp < 2; ++cp) {
            int j = j0 + cp * 16 + row_a;    // C/D: col = lane&15
            float s  = acc[cp][q] * (1.f / 64.f);
            float ra = r_acc[robase + (size_t)i * NN + j];
            float rn = fminf(fmaxf(0.7f * ra + 0.3f * s, -2.f), 2.f);
            r_out[robase + (size_t)i * NN + j] = rn;
            float cpl = (i == j) ? 0.f
                        : (1.f / (1.f + __expf(-cond * rn))) * gi * g_j[cp];
            c_bf[robase + (size_t)i * NN + j] = __float2bfloat16(cpl);
            rs[q] += cpl;
        }
    }

    // reduce each row's partial over the 16 lanes sharing (kg,q)
    #pragma unroll
    for (int q = 0; q < 4; ++q) {
        float v = rs[q];
        v += __shfl_xor(v, 1);
        v += __shfl_xor(v, 2);
        v += __shfl_xor(v, 4);
        v += __shfl_xor(v, 8);
        if ((l & 15) == 0) atomicAdd(&rowsum[b * NN + i_base + q], v);
    }
}

// ---- kernel 3: partial[jc] = C[:, jc-chunk] @ V[jc-chunk, :]  (MFMA, bf16 out) ----
// grid (16 j-chunks, 16 i-tiles, 2 batches) = 512 blocks.
__global__ __launch_bounds__(256) void gather_kernel(
    const __hip_bfloat16* __restrict__ c_bf,
    const __hip_bfloat16* __restrict__ valT,
    __hip_bfloat16* __restrict__ part)
{
    const int tid = threadIdx.x;
    const int l  = tid & 63;
    const int w  = tid >> 6;
    const int jc = blockIdx.x;               // j0 = jc*64
    const int i0 = blockIdx.y * 64;
    const int b  = blockIdx.z;

    const int row_a = l & 15;
    const int kg    = l >> 4;

    const bf16x8* Cv = (const bf16x8*)(c_bf + (size_t)b * NN * NN);   // [i][j/8]
    const bf16x8* Vv = (const bf16x8*)(valT + (size_t)b * DD * NN);   // [d][j/8]

    f32x4 acc[8];
    #pragma unroll
    for (int dt = 0; dt < 8; ++dt) acc[dt] = (f32x4){0.f, 0.f, 0.f, 0.f};

    #pragma unroll
    for (int s = 0; s < 2; ++s) {
        int kv = jc * 8 + s * 4 + kg;        // j = kv*8
        bf16x8 a = Cv[(size_t)(i0 + w * 16 + row_a) * (NN / 8) + kv];
        #pragma unroll
        for (int dt = 0; dt < 8; ++dt) {
            bf16x8 bb = Vv[(size_t)(dt * 16 + row_a) * (NN / 8) + kv];
            acc[dt] = __builtin_amdgcn_mfma_f32_16x16x32_bf16(a, bb, acc[dt], 0, 0, 0);
        }
    }

    __hip_bfloat16* pb = part + ((size_t)jc * 2 + b) * NN * DD;
    #pragma unroll
    for (int dt = 0; dt < 8; ++dt) {
        #pragma unroll
        for (int q = 0; q < 4; ++q) {
            int i = i0 + w * 16 + kg * 4 + q;
            int d = dt * 16 + row_a;
            pb[(size_t)i * DD + d] = __float2bfloat16(acc[dt][q]);
        }
    }
}

// ---- kernel 4: field = (sum_jc part[jc]) / rowsum ----
__global__ __launch_bounds__(256) void reduce_kernel(
    const __hip_bfloat16* __restrict__ part,
    const float* __restrict__ rowsum,
    float* __restrict__ field)
{
    int p   = blockIdx.x * 256 + threadIdx.x;   // pair index (131072 total)
    int b   = p >> 16;
    int rem = p & 65535;
    int i   = rem >> 6;
    int d2  = (rem & 63) * 2;
    size_t base = ((size_t)b * NN + i) * DD + d2;

    float s0 = 0.f, s1 = 0.f;
    #pragma unroll
    for (int jc = 0; jc < 16; ++jc) {
        unsigned int u = *(const unsigned int*)(part + (size_t)jc * 2 * NN * DD + base);
        s0 += __uint_as_float(u << 16);           // low ushort  = elem d2
        s1 += __uint_as_float(u & 0xffff0000u);   // high ushort = elem d2+1
    }
    float inv = 1.0f / (rowsum[b * NN + i] + 1e-8f);
    float2 o = {s0 * inv, s1 * inv};
    *(float2*)(field + base) = o;
}

// ---------------- launch ----------------
extern "C" void kernel_launch(void* const* d_in, const int* in_sizes, int n_in,
                              void* d_out, int out_size, void* d_ws, size_t ws_size,
                              hipStream_t stream) {
    const float* states = (const float*)d_in[0];
    const float* gates  = (const float*)d_in[1];
    const float* r_acc  = (const float*)d_in[2];
    const float* W_in   = (const float*)d_in[3];
    const float* W_out  = (const float*)d_in[4];
    const float* cond   = (const float*)d_in[5];

    float* field = (float*)d_out;                 // (2,1024,128)
    float* r_out = field + 2 * NN * DD;           // (2,1024,1024)

    char* ws = (char*)d_ws;
    __hip_bfloat16* M_bf   = (__hip_bfloat16*)ws;                       // 512 KB @ 0
    __hip_bfloat16* valT   = (__hip_bfloat16*)(ws + (512 << 10));       // 512 KB @ 512K
    __hip_bfloat16* c_bf   = (__hip_bfloat16*)(ws + (1 << 20));         // 4 MB  @ 1M
    float*          rowsum = (float*)(ws + (5 << 20));                  // 8 KB  @ 5M
    __hip_bfloat16* part   = (__hip_bfloat16*)(ws + (6 << 20));         // 8 MB  @ 6M

    hipLaunchKernelGGL(init_kernel, dim3(8), dim3(256), 0, stream, rowsum);
    hipLaunchKernelGGL(prep_kernel, dim3(512), dim3(256), 0, stream,
                       states, gates, W_in, W_out, M_bf, valT);
    hipLaunchKernelGGL(resonance_kernel, dim3(32, 16, 2), dim3(256), 0, stream,
                       M_bf, r_acc, gates, cond, r_out, c_bf, rowsum);
    hipLaunchKernelGGL(gather_kernel, dim3(16, 16, 2), dim3(256), 0, stream,
                       c_bf, valT, part);
    hipLaunchKernelGGL(reduce_kernel, dim3(512), dim3(256), 0, stream,
                       part, rowsum, field);
}

// Round 3
// 101.138 us; speedup vs baseline: 1.3885x; 1.0931x over previous
//
#include <hip/hip_runtime.h>
#include <hip/hip_bf16.h>

using bf16x8 = __attribute__((ext_vector_type(8))) short;   // 8 bf16 (16 B)
using bf16x4 = __attribute__((ext_vector_type(4))) short;   // 4 bf16 (8 B)
using f32x4  = __attribute__((ext_vector_type(4))) float;   // MFMA C/D frag

#define NN 1024
#define DD 128

__device__ __forceinline__ short bf16bits(float f) {
    __hip_bfloat16 t = __float2bfloat16(f);
    return *(short*)&t;
}

// ---- kernel 1: h = S@Win^T -> M(bf16); valT = ((S*g)@Wout^T)^T (bf16) ----
// 512 blocks, 4 rows each.
__global__ __launch_bounds__(256) void prep_kernel(
    const float* __restrict__ states, const float* __restrict__ gates,
    const float* __restrict__ W_in, const float* __restrict__ W_out,
    __hip_bfloat16* __restrict__ M_bf, __hip_bfloat16* __restrict__ valT)
{
    __shared__ float s_state[4 * 128];
    __shared__ float s_WinT[32 * 129];   // [k][d], pad -> conflict-free
    __shared__ float s_WoutT[32 * 129];
    __shared__ float s_v[4][128];
    __shared__ float s_g[4];

    const int tid = threadIdx.x;
    const int b  = blockIdx.x >> 8;          // 256 blocks per batch
    const int n0 = (blockIdx.x & 255) * 4;   // 4 rows per block

    const float* sb = states + ((size_t)b * NN + n0) * DD;
    if (tid < 128) ((float4*)s_state)[tid] = ((const float4*)sb)[tid];
    if (tid < 4)   s_g[tid] = gates[b * NN + n0 + tid];

    const int c  = tid & 127;   // output column d
    const int rg = tid >> 7;    // rows rg*2 .. rg*2+1
    float acc_h[2] = {0.f, 0.f};
    float acc_v[2] = {0.f, 0.f};

    const int kq = tid & 7;     // k-quad within 32-chunk
    const int dl = tid >> 3;    // 0..31
    for (int k0 = 0; k0 < 128; k0 += 32) {
        __syncthreads();
        #pragma unroll
        for (int dp = 0; dp < 4; ++dp) {
            int d = dp * 32 + dl;
            float4 w1 = *(const float4*)(W_in  + d * 128 + k0 + kq * 4);
            float4 w2 = *(const float4*)(W_out + d * 128 + k0 + kq * 4);
            s_WinT [(kq * 4 + 0) * 129 + d] = w1.x;
            s_WinT [(kq * 4 + 1) * 129 + d] = w1.y;
            s_WinT [(kq * 4 + 2) * 129 + d] = w1.z;
            s_WinT [(kq * 4 + 3) * 129 + d] = w1.w;
            s_WoutT[(kq * 4 + 0) * 129 + d] = w2.x;
            s_WoutT[(kq * 4 + 1) * 129 + d] = w2.y;
            s_WoutT[(kq * 4 + 2) * 129 + d] = w2.z;
            s_WoutT[(kq * 4 + 3) * 129 + d] = w2.w;
        }
        __syncthreads();
        #pragma unroll
        for (int k2 = 0; k2 < 32; ++k2) {
            float w1 = s_WinT [k2 * 129 + c];
            float w2 = s_WoutT[k2 * 129 + c];
            #pragma unroll
            for (int r = 0; r < 2; ++r) {
                float s = s_state[(rg * 2 + r) * 128 + k0 + k2];
                acc_h[r] = fmaf(s, w1, acc_h[r]);
                acc_v[r] = fmaf(s, w2, acc_v[r]);
            }
        }
    }

    #pragma unroll
    for (int r = 0; r < 2; ++r) {
        int row = rg * 2 + r;
        float hm = acc_h[r] + 1e-8f;         // my (h+eps)
        float hp = __shfl_xor(hm, 1);        // pair partner (same wave)
        float x = (c & 1) ? hp : hm;
        float y = (c & 1) ? hm : hp;
        float r2 = x * x + y * y;
        float out;
        if (r2 > 0.f) out = ((c & 1) ? y : x) * rsqrtf(r2);
        else          out = (c & 1) ? 0.f : 1.f;   // atan2(0,0)=0 -> cos=1,sin=0
        M_bf[((size_t)b * NN + n0 + row) * DD + c] = __float2bfloat16(out);
        s_v[row][c] = acc_v[r] * s_g[row];
    }
    __syncthreads();

    if (tid < 128) {   // valT[d][n0..n0+3] packed 8B store
        bf16x4 pk;
        #pragma unroll
        for (int r = 0; r < 4; ++r) pk[r] = bf16bits(s_v[r][tid]);
        *(bf16x4*)(valT + ((size_t)b * DD + tid) * NN + n0) = pk;
    }
}

// ---- kernel 2 (fused): S=M@M^T/64 -> r_out; coupling in regs -> LDS -> PV MFMA ----
// tile 32 i x 64 j; grid (16 jt, 32 it, 2 b) = 1024 blocks; 4 waves/block.
__global__ __launch_bounds__(256) void fused_kernel(
    const __hip_bfloat16* __restrict__ M_bf,
    const __hip_bfloat16* __restrict__ valT,
    const float* __restrict__ r_acc,
    const float* __restrict__ gates,
    const float* __restrict__ cond_ptr,
    float* __restrict__ r_out,
    __hip_bfloat16* __restrict__ part,
    float* __restrict__ part_rs)
{
    __shared__ __align__(16) __hip_bfloat16 s_cpl[2][16][72];  // [wi][i_loc][j_loc], pad 8
    __shared__ float s_rs[32][2];

    const int tid = threadIdx.x;
    const int l  = tid & 63;
    const int w  = tid >> 6;
    const int wi = w & 1;            // i-slab (16 rows)
    const int wj = w >> 1;           // j-half (S phase) / d-half (PV phase)
    const int row_a = l & 15;
    const int kg    = l >> 4;

    const int jt = blockIdx.x;
    const int j0 = jt * 64;
    const int i0 = blockIdx.y * 32;
    const int b  = blockIdx.z;

    const bf16x8* Mv = (const bf16x8*)(M_bf + (size_t)b * NN * DD);
    const bf16x8* Vv = (const bf16x8*)(valT + (size_t)b * DD * NN);

    // ---- S phase: 16 x 32 per wave ----
    f32x4 acc[2];
    acc[0] = (f32x4){0.f, 0.f, 0.f, 0.f};
    acc[1] = (f32x4){0.f, 0.f, 0.f, 0.f};
    #pragma unroll
    for (int ks = 0; ks < 4; ++ks) {
        int kv = ks * 4 + kg;
        bf16x8 a = Mv[(size_t)(i0 + wi * 16 + row_a) * 16 + kv];
        #pragma unroll
        for (int cp = 0; cp < 2; ++cp) {
            bf16x8 bb = Mv[(size_t)(j0 + wj * 32 + cp * 16 + row_a) * 16 + kv];
            acc[cp] = __builtin_amdgcn_mfma_f32_16x16x32_bf16(a, bb, acc[cp], 0, 0, 0);
        }
    }

    float cond = fminf(fmaxf(cond_ptr[0], -5.f), 5.f);
    const int i_base = i0 + wi * 16 + kg * 4;

    float g_j[2], g_i[4];
    #pragma unroll
    for (int cp = 0; cp < 2; ++cp) g_j[cp] = gates[b * NN + j0 + wj * 32 + cp * 16 + row_a];
    #pragma unroll
    for (int q = 0; q < 4; ++q)    g_i[q]  = gates[b * NN + i_base + q];

    const size_t robase = (size_t)b * NN * NN;
    float rs[4] = {0.f, 0.f, 0.f, 0.f};

    #pragma unroll
    for (int q = 0; q < 4; ++q) {
        int i = i_base + q;     // C/D: row = kg*4+q  [m89-verified]
        float gi = g_i[q];
        #pragma unroll
        for (int cp = 0; cp < 2; ++cp) {
            int jl = wj * 32 + cp * 16 + row_a;
            int j  = j0 + jl;    // C/D: col = lane&15
            float s  = acc[cp][q] * (1.f / 64.f);
            float ra = r_acc[robase + (size_t)i * NN + j];
            float rn = fminf(fmaxf(0.7f * ra + 0.3f * s, -2.f), 2.f);
            r_out[robase + (size_t)i * NN + j] = rn;
            float cpl = (i == j) ? 0.f
                        : (1.f / (1.f + __expf(-cond * rn))) * gi * g_j[cp];
            rs[q] += cpl;
            s_cpl[wi][kg * 4 + q][jl] = __float2bfloat16(cpl);
        }
    }

    // rowsum partials: reduce over the 16 row_a lanes
    #pragma unroll
    for (int q = 0; q < 4; ++q) {
        float v = rs[q];
        v += __shfl_xor(v, 1);
        v += __shfl_xor(v, 2);
        v += __shfl_xor(v, 4);
        v += __shfl_xor(v, 8);
        if (row_a == 0) s_rs[wi * 16 + kg * 4 + q][wj] = v;
    }
    __syncthreads();

    // ---- PV phase: field_part(16 i x 64 d per wave) = cpl(16x64) @ V^T ----
    f32x4 pacc[4];
    #pragma unroll
    for (int dt = 0; dt < 4; ++dt) pacc[dt] = (f32x4){0.f, 0.f, 0.f, 0.f};

    #pragma unroll
    for (int ks2 = 0; ks2 < 2; ++ks2) {
        bf16x8 a = *(const bf16x8*)&s_cpl[wi][row_a][ks2 * 32 + kg * 8];
        #pragma unroll
        for (int dt = 0; dt < 4; ++dt) {
            int d = (wj * 4 + dt) * 16 + row_a;
            bf16x8 bb = Vv[(size_t)d * (NN / 8) + (j0 >> 3) + ks2 * 4 + kg];
            pacc[dt] = __builtin_amdgcn_mfma_f32_16x16x32_bf16(a, bb, pacc[dt], 0, 0, 0);
        }
    }

    __hip_bfloat16* pb = part + ((size_t)jt * 2 + b) * NN * DD;
    #pragma unroll
    for (int dt = 0; dt < 4; ++dt) {
        #pragma unroll
        for (int q = 0; q < 4; ++q) {
            int i = i0 + wi * 16 + kg * 4 + q;
            int d = (wj * 4 + dt) * 16 + row_a;
            pb[(size_t)i * DD + d] = __float2bfloat16(pacc[dt][q]);
        }
    }

    if (tid < 32)
        part_rs[((size_t)jt * 2 + b) * NN + i0 + tid] = s_rs[tid][0] + s_rs[tid][1];
}

// ---- kernel 3: field = (sum_jt part[jt]) / (sum_jt rs[jt] + 1e-8) ----
__global__ __launch_bounds__(256) void reduce_kernel(
    const __hip_bfloat16* __restrict__ part,
    const float* __restrict__ part_rs,
    float* __restrict__ field)
{
    int t   = blockIdx.x * 256 + threadIdx.x;   // 65536 total
    int b   = t >> 15;
    int rem = t & 32767;
    int i   = rem >> 5;
    int d4  = (rem & 31) * 4;
    size_t ibase = (size_t)i * DD + d4;

    float s0 = 0.f, s1 = 0.f, s2 = 0.f, s3 = 0.f, rsum = 0.f;
    #pragma unroll
    for (int jt = 0; jt < 16; ++jt) {
        size_t slab = ((size_t)jt * 2 + b);
        uint2 u = *(const uint2*)(part + slab * NN * DD + ibase);
        s0 += __uint_as_float(u.x << 16);
        s1 += __uint_as_float(u.x & 0xffff0000u);
        s2 += __uint_as_float(u.y << 16);
        s3 += __uint_as_float(u.y & 0xffff0000u);
        rsum += part_rs[slab * NN + i];
    }
    float inv = 1.0f / (rsum + 1e-8f);
    float4 o = {s0 * inv, s1 * inv, s2 * inv, s3 * inv};
    *(float4*)(field + ((size_t)b * NN + i) * DD + d4) = o;
}

// ---------------- launch ----------------
extern "C" void kernel_launch(void* const* d_in, const int* in_sizes, int n_in,
                              void* d_out, int out_size, void* d_ws, size_t ws_size,
                              hipStream_t stream) {
    const float* states = (const float*)d_in[0];
    const float* gates  = (const float*)d_in[1];
    const float* r_acc  = (const float*)d_in[2];
    const float* W_in   = (const float*)d_in[3];
    const float* W_out  = (const float*)d_in[4];
    const float* cond   = (const float*)d_in[5];

    float* field = (float*)d_out;                 // (2,1024,128)
    float* r_out = field + 2 * NN * DD;           // (2,1024,1024)

    char* ws = (char*)d_ws;
    __hip_bfloat16* M_bf    = (__hip_bfloat16*)ws;                   // 512 KB @ 0
    __hip_bfloat16* valT    = (__hip_bfloat16*)(ws + (512 << 10));   // 512 KB @ 512K
    __hip_bfloat16* part    = (__hip_bfloat16*)(ws + (1 << 20));     // 8 MB  @ 1M
    float*          part_rs = (float*)(ws + (9 << 20));              // 128 KB @ 9M

    hipLaunchKernelGGL(prep_kernel, dim3(512), dim3(256), 0, stream,
                       states, gates, W_in, W_out, M_bf, valT);
    hipLaunchKernelGGL(fused_kernel, dim3(16, 32, 2), dim3(256), 0, stream,
                       M_bf, valT, r_acc, gates, cond, r_out, part, part_rs);
    hipLaunchKernelGGL(reduce_kernel, dim3(256), dim3(256), 0, stream,
                       part, part_rs, field);
}

// Round 4
// 98.084 us; speedup vs baseline: 1.4318x; 1.0311x over previous
//
#include <hip/hip_runtime.h>
#include <hip/hip_bf16.h>

using bf16x8 = __attribute__((ext_vector_type(8))) short;   // 8 bf16 (16 B)
using f32x4  = __attribute__((ext_vector_type(4))) float;   // MFMA C/D frag

#define NN 1024
#define DD 128

__device__ __forceinline__ short bf16b(float f) {
    __hip_bfloat16 t = __float2bfloat16(f);
    return *(short*)&t;
}

__device__ __forceinline__ bf16x8 cvt8(const float* __restrict__ p) {
    float4 a = *(const float4*)p;
    float4 b = *(const float4*)(p + 4);
    bf16x8 r;
    r[0] = bf16b(a.x); r[1] = bf16b(a.y); r[2] = bf16b(a.z); r[3] = bf16b(a.w);
    r[4] = bf16b(b.x); r[5] = bf16b(b.y); r[6] = bf16b(b.z); r[7] = bf16b(b.w);
    return r;
}

// ---- kernel 1 (MFMA): h=S@Win^T -> M(bf16); valT=((S@Wout^T)*g)^T (bf16) ----
// grid 128 blocks (64 row-tiles x 2 batches), 4 waves; wave w covers cols w*32..+31
// of BOTH gemms. B-operand = W rows as stored (y = x@W^T). f32->bf16 cvt in regs.
__global__ __launch_bounds__(256) void prep_kernel(
    const float* __restrict__ states, const float* __restrict__ gates,
    const float* __restrict__ W_in, const float* __restrict__ W_out,
    __hip_bfloat16* __restrict__ M_bf, __hip_bfloat16* __restrict__ valT)
{
    __shared__ __align__(16) short s_m[16][136];    // [n_loc][d], pad->16B-aligned rows
    __shared__ __align__(16) short s_vT[128][24];   // [d][n_loc], 48B rows

    const int tid = threadIdx.x;
    const int l = tid & 63, w = tid >> 6;
    const int row_a = l & 15, kg = l >> 4;
    const int b  = blockIdx.x >> 6;
    const int n0 = (blockIdx.x & 63) * 16;
    const int colbase = w * 32;

    const float* A = states + ((size_t)b * NN + n0) * DD;

    f32x4 accH[2], accV[2];
    #pragma unroll
    for (int cp = 0; cp < 2; ++cp) {
        accH[cp] = (f32x4){0.f, 0.f, 0.f, 0.f};
        accV[cp] = (f32x4){0.f, 0.f, 0.f, 0.f};
    }

    #pragma unroll
    for (int ks = 0; ks < 4; ++ks) {
        int koff = (ks * 4 + kg) * 8;
        bf16x8 a = cvt8(A + row_a * DD + koff);
        #pragma unroll
        for (int cp = 0; cp < 2; ++cp) {
            int d = colbase + cp * 16 + row_a;
            bf16x8 b1 = cvt8(W_in  + d * DD + koff);
            bf16x8 b2 = cvt8(W_out + d * DD + koff);
            accH[cp] = __builtin_amdgcn_mfma_f32_16x16x32_bf16(a, b1, accH[cp], 0, 0, 0);
            accV[cp] = __builtin_amdgcn_mfma_f32_16x16x32_bf16(a, b2, accV[cp], 0, 0, 0);
        }
    }

    float g[4];
    #pragma unroll
    for (int q = 0; q < 4; ++q) g[q] = gates[b * NN + n0 + kg * 4 + q];

    const bool odd = (row_a & 1) != 0;
    #pragma unroll
    for (int cp = 0; cp < 2; ++cp) {
        #pragma unroll
        for (int q = 0; q < 4; ++q) {
            float hm = accH[cp][q] + 1e-8f;       // my (h+eps); col parity = lane parity
            float hp = __shfl_xor(hm, 1);         // pair partner (adjacent col/lane)
            float x = odd ? hp : hm;
            float y = odd ? hm : hp;
            float r2 = x * x + y * y;
            float out;
            if (r2 > 0.f) out = (odd ? y : x) * rsqrtf(r2);
            else          out = odd ? 0.f : 1.f;  // atan2(0,0)=0 -> cos=1,sin=0
            s_m[kg * 4 + q][colbase + cp * 16 + row_a] = bf16b(out);
            s_vT[colbase + cp * 16 + row_a][kg * 4 + q] = bf16b(accV[cp][q] * g[q]);
        }
    }
    __syncthreads();

    {   // M rows: 16B packed stores
        int r = tid >> 4, seg = tid & 15;
        bf16x8 v = *(const bf16x8*)&s_m[r][seg * 8];
        *(bf16x8*)(M_bf + ((size_t)b * NN + n0 + r) * DD + seg * 8) = v;
    }
    {   // valT[d][n0..n0+15]: 16B packed stores
        int d = tid >> 1, half = tid & 1;
        bf16x8 v = *(const bf16x8*)&s_vT[d][half * 8];
        *(bf16x8*)(valT + ((size_t)b * DD + d) * NN + n0 + half * 8) = v;
    }
}

// ---- kernel 2 (fused): S=M@M^T/64 -> r_out; coupling regs->LDS->PV MFMA ----
// tile 32 i x 128 j; grid (8 jt, 32 it, 2 b) = 512 blocks; 4 waves.
__global__ __launch_bounds__(256) void fused_kernel(
    const __hip_bfloat16* __restrict__ M_bf,
    const __hip_bfloat16* __restrict__ valT,
    const float* __restrict__ r_acc,
    const float* __restrict__ gates,
    const float* __restrict__ cond_ptr,
    float* __restrict__ r_out,
    __hip_bfloat16* __restrict__ part,
    float* __restrict__ part_rs)
{
    __shared__ __align__(16) short s_cpl[2][16][136];  // [wi][i_loc][j_loc]
    __shared__ float s_rs[32][2];

    const int tid = threadIdx.x;
    const int l  = tid & 63;
    const int w  = tid >> 6;
    const int wi = w & 1;            // i-slab (16 rows)
    const int wj = w >> 1;           // j-half (S) / d-half (PV)
    const int row_a = l & 15;
    const int kg    = l >> 4;

    const int jt = blockIdx.x;
    const int j0 = jt * 128;
    const int i0 = blockIdx.y * 32;
    const int b  = blockIdx.z;

    const bf16x8* Mv = (const bf16x8*)(M_bf + (size_t)b * NN * DD);
    const bf16x8* Vv = (const bf16x8*)(valT + (size_t)b * DD * NN);

    // ---- S phase: 16 x 64 per wave ----
    f32x4 acc[4];
    #pragma unroll
    for (int cp = 0; cp < 4; ++cp) acc[cp] = (f32x4){0.f, 0.f, 0.f, 0.f};

    #pragma unroll
    for (int ks = 0; ks < 4; ++ks) {
        int kv = ks * 4 + kg;
        bf16x8 a = Mv[(size_t)(i0 + wi * 16 + row_a) * 16 + kv];
        #pragma unroll
        for (int cp = 0; cp < 4; ++cp) {
            bf16x8 bb = Mv[(size_t)(j0 + wj * 64 + cp * 16 + row_a) * 16 + kv];
            acc[cp] = __builtin_amdgcn_mfma_f32_16x16x32_bf16(a, bb, acc[cp], 0, 0, 0);
        }
    }

    float cond = fminf(fmaxf(cond_ptr[0], -5.f), 5.f);
    const int i_base = i0 + wi * 16 + kg * 4;

    float g_j[4], g_i[4];
    #pragma unroll
    for (int cp = 0; cp < 4; ++cp) g_j[cp] = gates[b * NN + j0 + wj * 64 + cp * 16 + row_a];
    #pragma unroll
    for (int q = 0; q < 4; ++q)    g_i[q]  = gates[b * NN + i_base + q];

    const size_t robase = (size_t)b * NN * NN;
    float rs[4] = {0.f, 0.f, 0.f, 0.f};

    #pragma unroll
    for (int q = 0; q < 4; ++q) {
        int i = i_base + q;     // C/D: row = kg*4+q  [m89-verified]
        float gi = g_i[q];
        #pragma unroll
        for (int cp = 0; cp < 4; ++cp) {
            int jl = wj * 64 + cp * 16 + row_a;
            int j  = j0 + jl;    // C/D: col = lane&15
            float s  = acc[cp][q] * (1.f / 64.f);
            float ra = r_acc[robase + (size_t)i * NN + j];
            float rn = fminf(fmaxf(0.7f * ra + 0.3f * s, -2.f), 2.f);
            r_out[robase + (size_t)i * NN + j] = rn;
            float cpl = (i == j) ? 0.f
                        : (1.f / (1.f + __expf(-cond * rn))) * gi * g_j[cp];
            rs[q] += cpl;
            s_cpl[wi][kg * 4 + q][jl] = bf16b(cpl);
        }
    }

    #pragma unroll
    for (int q = 0; q < 4; ++q) {
        float v = rs[q];
        v += __shfl_xor(v, 1);
        v += __shfl_xor(v, 2);
        v += __shfl_xor(v, 4);
        v += __shfl_xor(v, 8);
        if (row_a == 0) s_rs[wi * 16 + kg * 4 + q][wj] = v;
    }
    __syncthreads();

    // ---- PV phase: per wave 16 i x 64 d: cpl(16x128) @ V^T ----
    f32x4 pacc[4];
    #pragma unroll
    for (int dt = 0; dt < 4; ++dt) pacc[dt] = (f32x4){0.f, 0.f, 0.f, 0.f};

    #pragma unroll
    for (int ks2 = 0; ks2 < 4; ++ks2) {
        bf16x8 a = *(const bf16x8*)&s_cpl[wi][row_a][(ks2 * 4 + kg) * 8];
        #pragma unroll
        for (int dt = 0; dt < 4; ++dt) {
            int d = wj * 64 + dt * 16 + row_a;
            bf16x8 bb = Vv[(size_t)d * (NN / 8) + (j0 >> 3) + ks2 * 4 + kg];
            pacc[dt] = __builtin_amdgcn_mfma_f32_16x16x32_bf16(a, bb, pacc[dt], 0, 0, 0);
        }
    }

    __hip_bfloat16* pb = part + ((size_t)jt * 2 + b) * NN * DD;
    #pragma unroll
    for (int dt = 0; dt < 4; ++dt) {
        #pragma unroll
        for (int q = 0; q < 4; ++q) {
            int i = i0 + wi * 16 + kg * 4 + q;
            int d = wj * 64 + dt * 16 + row_a;
            pb[(size_t)i * DD + d] = __float2bfloat16(pacc[dt][q]);
        }
    }

    if (tid < 32)
        part_rs[((size_t)jt * 2 + b) * NN + i0 + tid] = s_rs[tid][0] + s_rs[tid][1];
}

// ---- kernel 3: field = (sum_jt part[jt]) / (sum_jt rs[jt] + 1e-8) ----
__global__ __launch_bounds__(256) void reduce_kernel(
    const __hip_bfloat16* __restrict__ part,
    const float* __restrict__ part_rs,
    float* __restrict__ field)
{
    int t   = blockIdx.x * 256 + threadIdx.x;   // 65536 total
    int b   = t >> 15;
    int rem = t & 32767;
    int i   = rem >> 5;
    int d4  = (rem & 31) * 4;
    size_t ibase = (size_t)i * DD + d4;

    float s0 = 0.f, s1 = 0.f, s2 = 0.f, s3 = 0.f, rsum = 0.f;
    #pragma unroll
    for (int jt = 0; jt < 8; ++jt) {
        size_t slab = ((size_t)jt * 2 + b);
        uint2 u = *(const uint2*)(part + slab * NN * DD + ibase);
        s0 += __uint_as_float(u.x << 16);
        s1 += __uint_as_float(u.x & 0xffff0000u);
        s2 += __uint_as_float(u.y << 16);
        s3 += __uint_as_float(u.y & 0xffff0000u);
        rsum += part_rs[slab * NN + i];
    }
    float inv = 1.0f / (rsum + 1e-8f);
    float4 o = {s0 * inv, s1 * inv, s2 * inv, s3 * inv};
    *(float4*)(field + ((size_t)b * NN + i) * DD + d4) = o;
}

// ---------------- launch ----------------
extern "C" void kernel_launch(void* const* d_in, const int* in_sizes, int n_in,
                              void* d_out, int out_size, void* d_ws, size_t ws_size,
                              hipStream_t stream) {
    const float* states = (const float*)d_in[0];
    const float* gates  = (const float*)d_in[1];
    const float* r_acc  = (const float*)d_in[2];
    const float* W_in   = (const float*)d_in[3];
    const float* W_out  = (const float*)d_in[4];
    const float* cond   = (const float*)d_in[5];

    float* field = (float*)d_out;                 // (2,1024,128)
    float* r_out = field + 2 * NN * DD;           // (2,1024,1024)

    char* ws = (char*)d_ws;
    __hip_bfloat16* M_bf    = (__hip_bfloat16*)ws;                   // 512 KB @ 0
    __hip_bfloat16* valT    = (__hip_bfloat16*)(ws + (512 << 10));   // 512 KB @ 512K
    __hip_bfloat16* part    = (__hip_bfloat16*)(ws + (1 << 20));     // 4 MB  @ 1M
    float*          part_rs = (float*)(ws + (5 << 20));              // 64 KB @ 5M

    hipLaunchKernelGGL(prep_kernel, dim3(128), dim3(256), 0, stream,
                       states, gates, W_in, W_out, M_bf, valT);
    hipLaunchKernelGGL(fused_kernel, dim3(8, 32, 2), dim3(256), 0, stream,
                       M_bf, valT, r_acc, gates, cond, r_out, part, part_rs);
    hipLaunchKernelGGL(reduce_kernel, dim3(256), dim3(256), 0, stream,
                       part, part_rs, field);
}